// Round 19
// baseline (479.769 us; speedup 1.0000x reference)
//
#include <hip/hip_runtime.h>
#include <hip/hip_bf16.h>
#include <stdint.h>

#define NN 100000
#define NE 1600000
#define DD 128
#define HH 256
#define LL 40

typedef __attribute__((ext_vector_type(8))) short short8;
typedef __attribute__((ext_vector_type(4))) float float4v;

__device__ __forceinline__ float bfu_lo(uint32_t u){ union{uint32_t i;float f;}v; v.i=u<<16; return v.f; }
__device__ __forceinline__ float bfu_hi(uint32_t u){ union{uint32_t i;float f;}v; v.i=u&0xFFFF0000u; return v.f; }
__device__ __forceinline__ float bf2f(uint16_t u){ union{uint32_t i;float f;}v; v.i=((uint32_t)u)<<16; return v.f; }
__device__ __forceinline__ uint16_t f2bf(float f){
  union{float f;uint32_t i;}v; v.f=f; uint32_t u=v.i;
  u += 0x7FFFu + ((u>>16)&1u); return (uint16_t)(u>>16);
}
__device__ __forceinline__ void split2(float f, short &hi, short &lo){
  uint16_t h = f2bf(f);
  hi = (short)h;
  lo = (short)f2bf(f - bf2f(h));
}
__device__ __forceinline__ float u2f(uint32_t u){ union{uint32_t i;float f;}v; v.i=u; return v.f; }

// ---------------- merged prep + count_edges, STRIPED + SPLIT COUNTERS ----------------
// r17: striping worked (82->70us, streaming hidden); storm = critical path. Avg degree 32
// -> ~32 serialized atomic round-trips per counts word. r18 fix: SPLIT counters (pairs
// < PC_HALF -> countsA, rest -> countsB) halves per-word chain length. Rank rebuild:
// A-edge pos = offs[r]+rankA; B-edge pos = offs[r]+cntA[r]+rankB, via packed per-node
// record {offs,cntA} written by scan_add (fill gather count unchanged). Stripe share
// raised to 1/4 (streaming only needs ~20us of machine; storm gets more concurrency).

__device__ __forceinline__ void swz_one(const float* __restrict__ W, uint16_t* __restrict__ Wf,
                                        int idx, int NCOL, int NTBP){
  int frag = idx >> 9, r = idx & 511, ln = r >> 3, j = r & 7;
  int kb = frag / NTBP, nt = frag - kb*NTBP;
  int k = kb*32 + ((ln >> 4) << 3) + j;
  int n = nt*16 + (ln & 15);
  float w = (n < NCOL) ? W[k*NCOL + n] : 0.f;
  Wf[idx] = f2bf(w);
}

#define PC_COUNT (NE/2)
#define PC_HALF  (PC_COUNT/2)
#define PC_CVT   (PC_COUNT + NN*64)
#define PC_W0    (PC_CVT + 16384)
#define PC_W1    (PC_W0 + 16384)
#define PC_W2    (PC_W1 + 16384)
#define PC_WM1   (PC_W2 + 32768)
#define PC_TOT   (PC_WM1 + 12288)
#define PC_CBLK  (PC_COUNT/256)         // 3125 count blocks
#define PC_NBLK  ((PC_TOT+255)/256)     // 28493 total blocks

__global__ __launch_bounds__(256) void prep_count(const float2* __restrict__ x,
                                                  const int* __restrict__ row,
                                                  int* __restrict__ countsA, int* __restrict__ countsB,
                                                  uint16_t* __restrict__ rank,
                                                  uint32_t* __restrict__ hb,
                                                  const float* __restrict__ W0, uint16_t* __restrict__ W0f,
                                                  const float* __restrict__ W1, uint16_t* __restrict__ W1f,
                                                  const float* __restrict__ W2, uint16_t* __restrict__ W2f,
                                                  const float* __restrict__ Wm1, uint16_t* __restrict__ Wm1f,
                                                  const float* __restrict__ Wm2, uint16_t* __restrict__ Wm2f){
  const int g = blockIdx.x;
  int idx;
  if ((g & 3) == 0 && (g >> 2) < PC_CBLK){
    idx = (g >> 2)*256 + threadIdx.x;                 // count segment [0, PC_COUNT)
  } else {
    int cb = (g + 3) >> 2; if (cb > PC_CBLK) cb = PC_CBLK;  // # count blocks before g
    idx = PC_COUNT + (g - cb)*256 + threadIdx.x;      // streaming segments
  }
  if (idx < PC_COUNT){
    int2 r2 = ((const int2*)row)[idx];
    int* __restrict__ cnt = (idx < PC_HALF) ? countsA : countsB;
    uint16_t a = (uint16_t)atomicAdd(&cnt[r2.x], 1);
    uint16_t b = (uint16_t)atomicAdd(&cnt[r2.y], 1);
    ((ushort2*)rank)[idx] = make_ushort2(a, b);
  } else if (idx < PC_CVT){
    int i = idx - PC_COUNT;
    float2 v = x[i];
    hb[i] = (uint32_t)f2bf(v.x) | ((uint32_t)f2bf(v.y) << 16);
  } else if (idx < PC_W0){
    swz_one(W0, W0f, idx - PC_CVT, 128, 8);
  } else if (idx < PC_W1){
    swz_one(W1, W1f, idx - PC_W0, 128, 8);
  } else if (idx < PC_W2){
    swz_one(W2, W2f, idx - PC_W1, 128, 8);
  } else if (idx < PC_WM1){
    swz_one(Wm1, Wm1f, idx - PC_W2, 256, 16);
  } else if (idx < PC_TOT){
    swz_one(Wm2, Wm2f, idx - PC_WM1, 40, 3);
  }
}

// ---------------- scan (deg = A+B; emits dinv = rsqrt(deg+1)) ----------------

__global__ __launch_bounds__(256) void scan_partial(const int* __restrict__ countsA,
                                                    const int* __restrict__ countsB,
                                                    int* __restrict__ offs, int* __restrict__ bsums,
                                                    float* __restrict__ dinv){
  __shared__ int sh[256];
  int t = threadIdx.x, i = blockIdx.x*256 + t;
  int v = (i < NN) ? (countsA[i] + countsB[i]) : 0;
  if (i < NN) dinv[i] = rsqrtf((float)(v + 1));
  sh[t] = v; __syncthreads();
  for (int d = 1; d < 256; d <<= 1){
    int x = (t >= d) ? sh[t-d] : 0;
    __syncthreads();
    sh[t] += x;
    __syncthreads();
  }
  if (i < NN) offs[i] = sh[t] - v;
  if (t == 255) bsums[blockIdx.x] = sh[255];
}

__global__ __launch_bounds__(512) void scan_block(int* __restrict__ bsums, int nb){
  __shared__ int sh[512];
  int t = threadIdx.x;
  int v = (t < nb) ? bsums[t] : 0;
  sh[t] = v; __syncthreads();
  for (int d = 1; d < 512; d <<= 1){
    int x = (t >= d) ? sh[t-d] : 0;
    __syncthreads();
    sh[t] += x;
    __syncthreads();
  }
  if (t < nb) bsums[t] = sh[t] - v;
}

// also writes the packed per-node record {offs_final, cntA} for fill_csr
__global__ __launch_bounds__(256) void scan_add(int* __restrict__ offs, const int* __restrict__ bsums,
                                                const int* __restrict__ countsA,
                                                uint2* __restrict__ rec){
  int i = blockIdx.x*256 + threadIdx.x;
  if (i < NN){
    int v = offs[i] + bsums[blockIdx.x];
    offs[i] = v;
    rec[i] = make_uint2((uint32_t)v, (uint32_t)countsA[i]);
  }
  if (i == 0) offs[NN] = NE;
}

// rank-based fill: atomic-free (round-5 lesson: returning atomics here = 120us).
// A-pairs (e2 < PC_HALF): p = rec.x + rank; B-pairs: p = rec.x + rec.y + rank.
__global__ __launch_bounds__(256) void fill_csr(const int* __restrict__ row, const int* __restrict__ col,
                                                const uint16_t* __restrict__ rank,
                                                const uint2* __restrict__ rec,
                                                const float* __restrict__ dinv,
                                                uint2* __restrict__ csr_cw){
  int e2 = blockIdx.x*256 + threadIdx.x;
  if (e2 < NE/2){
    int2 r2 = ((const int2*)row)[e2];
    int2 c2 = ((const int2*)col)[e2];
    ushort2 k2 = ((const ushort2*)rank)[e2];
    uint2 rx = rec[r2.x], ry = rec[r2.y];
    const uint32_t baseoff = (e2 < PC_HALF) ? 0u : 1u;   // B-half adds cntA
    int p0 = (int)(rx.x + (baseoff ? rx.y : 0u)) + (int)k2.x;
    int p1 = (int)(ry.x + (baseoff ? ry.y : 0u)) + (int)k2.y;
    uint2 v0, v1;
    v0.x = (uint32_t)c2.x;
    v1.x = (uint32_t)c2.y;
    union{float f;uint32_t i;}w0; w0.f = dinv[c2.x]; v0.y = w0.i;
    union{float f;uint32_t i;}w1; w1.f = dinv[c2.y]; v1.y = w1.i;
    csr_cw[p0] = v0;
    csr_cw[p1] = v1;
  }
}

// ---------------- fused layer: Hout(bf16) = relu( (A_norm @ hb) @ W + b ) ----------------
// Phase 1 scalarized (r6) + 16-deep compiler-scheduled batch (r11: 72.4->70.1us).
// agg is at its multi-resource equilibrium (~70us); left unchanged this round.

__global__ __launch_bounds__(256) void agg_gemm(const uint32_t* __restrict__ hb,
                                                const int* __restrict__ offs,
                                                const uint2* __restrict__ csr_cw,
                                                const float* __restrict__ dinv,
                                                const uint16_t* __restrict__ Wf,
                                                const float* __restrict__ bias,
                                                uint16_t* __restrict__ Hout){
  __shared__ float lds[16*129];
  __shared__ int ticket;
  const int lane = threadIdx.x & 63;
  const int rbase = blockIdx.x*16;   // NN % 16 == 0, all rows valid
  if (threadIdx.x == 0) ticket = 0;
  __syncthreads();

  // ---- phase 1: dynamic row claim (wave-uniform via readfirstlane) ----
  for (;;){
    int tk = 0;
    if (lane == 0) tk = atomicAdd(&ticket, 1);
    const int rl = __builtin_amdgcn_readfirstlane(tk);
    if (rl >= 16) break;

    const int w = rbase + rl;                  // uniform
    const int s = offs[w], e = offs[w+1];      // uniform -> s_load
    const float dr = dinv[w];                  // uniform -> s_load
    const uint32_t us = hb[((size_t)w << 6) + lane];

    float a0=0.f,a1=0.f,b0=0.f,b1=0.f,c0=0.f,c1=0.f,d0=0.f,d1=0.f;
    float e0=0.f,e1=0.f,f0=0.f,f1=0.f,g0=0.f,g1=0.f,h0=0.f,h1=0.f;
    int i = s;
    // 16-deep: 16 outstanding gathers per wave, compiler-scheduled
    for (; i + 16 <= e; i += 16){
      const uint2 p0=csr_cw[i],   p1=csr_cw[i+1],  p2=csr_cw[i+2],  p3=csr_cw[i+3];
      const uint2 p4=csr_cw[i+4], p5=csr_cw[i+5],  p6=csr_cw[i+6],  p7=csr_cw[i+7];
      const uint2 p8=csr_cw[i+8], p9=csr_cw[i+9],  pa=csr_cw[i+10], pb=csr_cw[i+11];
      const uint2 pc=csr_cw[i+12],pd=csr_cw[i+13], pe=csr_cw[i+14], pf=csr_cw[i+15];
      uint32_t u0=hb[((size_t)p0.x<<6)+lane], u1=hb[((size_t)p1.x<<6)+lane];
      uint32_t u2=hb[((size_t)p2.x<<6)+lane], u3=hb[((size_t)p3.x<<6)+lane];
      uint32_t u4=hb[((size_t)p4.x<<6)+lane], u5=hb[((size_t)p5.x<<6)+lane];
      uint32_t u6=hb[((size_t)p6.x<<6)+lane], u7=hb[((size_t)p7.x<<6)+lane];
      uint32_t u8=hb[((size_t)p8.x<<6)+lane], u9=hb[((size_t)p9.x<<6)+lane];
      uint32_t ua=hb[((size_t)pa.x<<6)+lane], ub=hb[((size_t)pb.x<<6)+lane];
      uint32_t uc=hb[((size_t)pc.x<<6)+lane], ud=hb[((size_t)pd.x<<6)+lane];
      uint32_t ue=hb[((size_t)pe.x<<6)+lane], uf=hb[((size_t)pf.x<<6)+lane];
      a0 += u2f(p0.y)*bfu_lo(u0); a1 += u2f(p0.y)*bfu_hi(u0);
      b0 += u2f(p1.y)*bfu_lo(u1); b1 += u2f(p1.y)*bfu_hi(u1);
      c0 += u2f(p2.y)*bfu_lo(u2); c1 += u2f(p2.y)*bfu_hi(u2);
      d0 += u2f(p3.y)*bfu_lo(u3); d1 += u2f(p3.y)*bfu_hi(u3);
      e0 += u2f(p4.y)*bfu_lo(u4); e1 += u2f(p4.y)*bfu_hi(u4);
      f0 += u2f(p5.y)*bfu_lo(u5); f1 += u2f(p5.y)*bfu_hi(u5);
      g0 += u2f(p6.y)*bfu_lo(u6); g1 += u2f(p6.y)*bfu_hi(u6);
      h0 += u2f(p7.y)*bfu_lo(u7); h1 += u2f(p7.y)*bfu_hi(u7);
      a0 += u2f(p8.y)*bfu_lo(u8); a1 += u2f(p8.y)*bfu_hi(u8);
      b0 += u2f(p9.y)*bfu_lo(u9); b1 += u2f(p9.y)*bfu_hi(u9);
      c0 += u2f(pa.y)*bfu_lo(ua); c1 += u2f(pa.y)*bfu_hi(ua);
      d0 += u2f(pb.y)*bfu_lo(ub); d1 += u2f(pb.y)*bfu_hi(ub);
      e0 += u2f(pc.y)*bfu_lo(uc); e1 += u2f(pc.y)*bfu_hi(uc);
      f0 += u2f(pd.y)*bfu_lo(ud); f1 += u2f(pd.y)*bfu_hi(ud);
      g0 += u2f(pe.y)*bfu_lo(ue); g1 += u2f(pe.y)*bfu_hi(ue);
      h0 += u2f(pf.y)*bfu_lo(uf); h1 += u2f(pf.y)*bfu_hi(uf);
    }
    if (i + 8 <= e){
      const uint2 p0=csr_cw[i],  p1=csr_cw[i+1], p2=csr_cw[i+2], p3=csr_cw[i+3];
      const uint2 p4=csr_cw[i+4],p5=csr_cw[i+5], p6=csr_cw[i+6], p7=csr_cw[i+7];
      uint32_t u0=hb[((size_t)p0.x<<6)+lane], u1=hb[((size_t)p1.x<<6)+lane];
      uint32_t u2=hb[((size_t)p2.x<<6)+lane], u3=hb[((size_t)p3.x<<6)+lane];
      uint32_t u4=hb[((size_t)p4.x<<6)+lane], u5=hb[((size_t)p5.x<<6)+lane];
      uint32_t u6=hb[((size_t)p6.x<<6)+lane], u7=hb[((size_t)p7.x<<6)+lane];
      a0 += u2f(p0.y)*bfu_lo(u0); a1 += u2f(p0.y)*bfu_hi(u0);
      b0 += u2f(p1.y)*bfu_lo(u1); b1 += u2f(p1.y)*bfu_hi(u1);
      c0 += u2f(p2.y)*bfu_lo(u2); c1 += u2f(p2.y)*bfu_hi(u2);
      d0 += u2f(p3.y)*bfu_lo(u3); d1 += u2f(p3.y)*bfu_hi(u3);
      e0 += u2f(p4.y)*bfu_lo(u4); e1 += u2f(p4.y)*bfu_hi(u4);
      f0 += u2f(p5.y)*bfu_lo(u5); f1 += u2f(p5.y)*bfu_hi(u5);
      g0 += u2f(p6.y)*bfu_lo(u6); g1 += u2f(p6.y)*bfu_hi(u6);
      h0 += u2f(p7.y)*bfu_lo(u7); h1 += u2f(p7.y)*bfu_hi(u7);
      i += 8;
    }
    if (i + 4 <= e){
      const uint2 p0=csr_cw[i], p1=csr_cw[i+1], p2=csr_cw[i+2], p3=csr_cw[i+3];
      uint32_t u0=hb[((size_t)p0.x<<6)+lane], u1=hb[((size_t)p1.x<<6)+lane];
      uint32_t u2=hb[((size_t)p2.x<<6)+lane], u3=hb[((size_t)p3.x<<6)+lane];
      a0 += u2f(p0.y)*bfu_lo(u0); a1 += u2f(p0.y)*bfu_hi(u0);
      b0 += u2f(p1.y)*bfu_lo(u1); b1 += u2f(p1.y)*bfu_hi(u1);
      c0 += u2f(p2.y)*bfu_lo(u2); c1 += u2f(p2.y)*bfu_hi(u2);
      d0 += u2f(p3.y)*bfu_lo(u3); d1 += u2f(p3.y)*bfu_hi(u3);
      i += 4;
    }
    for (; i < e; ++i){
      const uint2 p = csr_cw[i];
      uint32_t u = hb[((size_t)p.x<<6) + lane];
      a0 += u2f(p.y)*bfu_lo(u); a1 += u2f(p.y)*bfu_hi(u);
    }
    float r0 = (((a0+b0)+(c0+d0)) + ((e0+f0)+(g0+h0))) + dr*bfu_lo(us);
    float r1 = (((a1+b1)+(c1+d1)) + ((e1+f1)+(g1+h1))) + dr*bfu_hi(us);
    lds[rl*129 + 2*lane]     = r0*dr;
    lds[rl*129 + 2*lane + 1] = r1*dr;
  }
  __syncthreads();

  // ---- phase 2: 16x128 GEMM tile; this wave covers n-tiles 2*wid, 2*wid+1 ----
  const int wid = threadIdx.x >> 6;
  const int mr = lane & 15;
  const int ko = (lane >> 4) << 3;
  float4v acc[2];
  { float4v z = {0.f,0.f,0.f,0.f}; acc[0] = z; acc[1] = z; }
#pragma unroll
  for (int kb = 0; kb < 4; ++kb){
    short8 ah, al;
#pragma unroll
    for (int j = 0; j < 8; ++j){
      float f = lds[mr*129 + kb*32 + ko + j];
      short h, l; split2(f, h, l); ah[j] = h; al[j] = l;
    }
#pragma unroll
    for (int t = 0; t < 2; ++t){
      int nt = wid*2 + t;
      short8 bf = *(const short8*)&Wf[(kb*8 + nt)*512 + lane*8];
      acc[t] = __builtin_amdgcn_mfma_f32_16x16x32_bf16(ah, bf, acc[t], 0, 0, 0);
      acc[t] = __builtin_amdgcn_mfma_f32_16x16x32_bf16(al, bf, acc[t], 0, 0, 0);
    }
  }
  const int col = lane & 15;
  const int rb  = (lane >> 4) * 4;
#pragma unroll
  for (int t = 0; t < 2; ++t){
    int n = (wid*2 + t)*16 + col;
    float bv = bias[n];
#pragma unroll
    for (int r = 0; r < 4; ++r){
      int m = rbase + rb + r;
      float v = acc[t][r] + bv;
      Hout[(size_t)m*128 + n] = f2bf(v > 0.f ? v : 0.f);
    }
  }
}

// ---------------- fused MLP: 2 m-tiles/wave, bf16 weights (1-term), stride-260 LDS ----------------

#define HS 260

__global__ __launch_bounds__(256) void mlp_fused(const uint16_t* __restrict__ Hb,
                                                 const uint16_t* __restrict__ W1f,
                                                 const float* __restrict__ b1,
                                                 const uint16_t* __restrict__ W2f,
                                                 const float* __restrict__ b2,
                                                 float* __restrict__ out, int M){
  __shared__ uint16_t hid[128*HS];
  const int lane = threadIdx.x & 63;
  const int wid = threadIdx.x >> 6;
  const int mbase = blockIdx.x*128 + wid*32;
  const int mr = lane & 15;
  const int a0r = (mbase + mr < M) ? (mbase + mr) : (M-1);
  const int a1r = (mbase + 16 + mr < M) ? (mbase + 16 + mr) : (M-1);
  const int ko = (lane >> 4) << 3;
  const int col = lane & 15;
  const int rb  = (lane >> 4) * 4;

  float4v acc1[16][2];
#pragma unroll
  for (int nt = 0; nt < 16; ++nt){ float4v z = {0.f,0.f,0.f,0.f}; acc1[nt][0] = z; acc1[nt][1] = z; }
#pragma unroll
  for (int kb = 0; kb < 4; ++kb){
    short8 af0 = *(const short8*)&Hb[(size_t)a0r*128 + kb*32 + ko];
    short8 af1 = *(const short8*)&Hb[(size_t)a1r*128 + kb*32 + ko];
#pragma unroll
    for (int nt = 0; nt < 16; ++nt){
      short8 bf = *(const short8*)&W1f[(kb*16 + nt)*512 + lane*8];
      acc1[nt][0] = __builtin_amdgcn_mfma_f32_16x16x32_bf16(af0, bf, acc1[nt][0], 0, 0, 0);
      acc1[nt][1] = __builtin_amdgcn_mfma_f32_16x16x32_bf16(af1, bf, acc1[nt][1], 0, 0, 0);
    }
  }
#pragma unroll
  for (int nt = 0; nt < 16; ++nt){
    float bv = b1[nt*16 + col];
#pragma unroll
    for (int mt = 0; mt < 2; ++mt){
#pragma unroll
      for (int r = 0; r < 4; ++r){
        float v = acc1[nt][mt][r] + bv;
        v = v > 0.f ? v : 0.f;
        hid[(wid*32 + mt*16 + rb + r)*HS + nt*16 + col] = f2bf(v);
      }
    }
  }
  __syncthreads();

  float4v acc2[3][2];
#pragma unroll
  for (int nt = 0; nt < 3; ++nt){ float4v z = {0.f,0.f,0.f,0.f}; acc2[nt][0] = z; acc2[nt][1] = z; }
#pragma unroll
  for (int kb = 0; kb < 8; ++kb){
    short8 a0 = *(const short8*)&hid[(wid*32 + mr)*HS + kb*32 + ko];
    short8 a1 = *(const short8*)&hid[(wid*32 + 16 + mr)*HS + kb*32 + ko];
#pragma unroll
    for (int nt = 0; nt < 3; ++nt){
      short8 bf = *(const short8*)&W2f[(kb*3 + nt)*512 + lane*8];
      acc2[nt][0] = __builtin_amdgcn_mfma_f32_16x16x32_bf16(a0, bf, acc2[nt][0], 0, 0, 0);
      acc2[nt][1] = __builtin_amdgcn_mfma_f32_16x16x32_bf16(a1, bf, acc2[nt][1], 0, 0, 0);
    }
  }
#pragma unroll
  for (int nt = 0; nt < 3; ++nt){
    int n = nt*16 + col;
    if (n < LL){
      float bv = b2[n];
#pragma unroll
      for (int mt = 0; mt < 2; ++mt){
#pragma unroll
        for (int r = 0; r < 4; ++r){
          int m = mbase + mt*16 + rb + r;
          if (m < M) out[(size_t)m*LL + n] = acc2[nt][mt][r] + bv;
        }
      }
    }
  }
}

// ---------------- launch ----------------

extern "C" void kernel_launch(void* const* d_in, const int* in_sizes, int n_in,
                              void* d_out, int out_size, void* d_ws, size_t ws_size,
                              hipStream_t stream){
  const float* x   = (const float*)d_in[0];
  const int*   ei  = (const int*)d_in[1];
  const float* W0  = (const float*)d_in[2];
  const float* b0  = (const float*)d_in[3];
  const float* W1  = (const float*)d_in[4];
  const float* b1  = (const float*)d_in[5];
  const float* W2  = (const float*)d_in[6];
  const float* b2  = (const float*)d_in[7];
  const float* Wm1 = (const float*)d_in[8];
  const float* bm1 = (const float*)d_in[9];
  const float* Wm2 = (const float*)d_in[10];
  const float* bm2 = (const float*)d_in[11];
  const int* row = ei;
  const int* col = ei + NE;

  char* ws = (char*)d_ws;
  size_t off = 0;
  auto alloc = [&](size_t bytes)->void*{
    void* p = ws + off;
    off += (bytes + 255) & ~(size_t)255;
    return p;
  };
  int*      counts2 = (int*)alloc((size_t)2*NN*4);   // countsA | countsB (one memset)
  int*      offs    = (int*)alloc(((size_t)NN+1)*4);
  int*      bsums   = (int*)alloc(1024*4);
  float*    dinv    = (float*)alloc((size_t)NN*4);
  uint2*    rec     = (uint2*)alloc((size_t)NN*8);
  uint16_t* rank    = (uint16_t*)alloc((size_t)NE*2);
  uint2*    csr_cw  = (uint2*)alloc((size_t)NE*8);
  uint16_t* W0f     = (uint16_t*)alloc(4*8*512*2);
  uint16_t* W1f     = (uint16_t*)alloc(4*8*512*2);
  uint16_t* W2f     = (uint16_t*)alloc(4*8*512*2);
  uint16_t* Wm1f    = (uint16_t*)alloc(4*16*512*2);
  uint16_t* Wm2f    = (uint16_t*)alloc(8*3*512*2);
  uint16_t* hb      = (uint16_t*)alloc((size_t)NN*DD*2);
  uint16_t* hb2     = (uint16_t*)alloc((size_t)NN*DD*2);
  int* countsA = counts2;
  int* countsB = counts2 + NN;

  hipMemsetAsync(counts2, 0, (size_t)2*NN*4, stream);
  prep_count<<<PC_NBLK, 256, 0, stream>>>((const float2*)x, row, countsA, countsB, rank, (uint32_t*)hb,
                                          W0, W0f, W1, W1f, W2, W2f, Wm1, Wm1f, Wm2, Wm2f);
  const int NB = (NN+255)/256;
  scan_partial<<<NB, 256, 0, stream>>>(countsA, countsB, offs, bsums, dinv);
  scan_block<<<1, 512, 0, stream>>>(bsums, NB);
  scan_add<<<NB, 256, 0, stream>>>(offs, bsums, countsA, rec);
  fill_csr<<<(NE/2+255)/256, 256, 0, stream>>>(row, col, rank, rec, dinv, csr_cw);

  const int LB = NN/16;   // 6250 blocks, 16 rows each

  agg_gemm<<<LB, 256, 0, stream>>>((const uint32_t*)hb,  offs, csr_cw, dinv, W0f, b0, hb2);
  agg_gemm<<<LB, 256, 0, stream>>>((const uint32_t*)hb2, offs, csr_cw, dinv, W1f, b1, hb);
  agg_gemm<<<LB, 256, 0, stream>>>((const uint32_t*)hb,  offs, csr_cw, dinv, W2f, b2, hb2);

  const int GB128 = (NN + 127)/128;
  mlp_fused<<<GB128, 256, 0, stream>>>(hb2, Wm1f, bm1, Wm2f, bm2, (float*)d_out, NN);
}

// Round 22
// 458.681 us; speedup vs baseline: 1.0460x; 1.0460x over previous
//
#include <hip/hip_runtime.h>
#include <hip/hip_bf16.h>
#include <stdint.h>

#define NN 100000
#define NE 1600000
#define DD 128
#define HH 256
#define LL 40

typedef __attribute__((ext_vector_type(8))) short short8;
typedef __attribute__((ext_vector_type(4))) float float4v;

__device__ __forceinline__ float bfu_lo(uint32_t u){ union{uint32_t i;float f;}v; v.i=u<<16; return v.f; }
__device__ __forceinline__ float bfu_hi(uint32_t u){ union{uint32_t i;float f;}v; v.i=u&0xFFFF0000u; return v.f; }
__device__ __forceinline__ float bf2f(uint16_t u){ union{uint32_t i;float f;}v; v.i=((uint32_t)u)<<16; return v.f; }
__device__ __forceinline__ uint16_t f2bf(float f){
  union{float f;uint32_t i;}v; v.f=f; uint32_t u=v.i;
  u += 0x7FFFu + ((u>>16)&1u); return (uint16_t)(u>>16);
}
__device__ __forceinline__ void split2(float f, short &hi, short &lo){
  uint16_t h = f2bf(f);
  hi = (short)h;
  lo = (short)f2bf(f - bf2f(h));
}
__device__ __forceinline__ float u2f(uint32_t u){ union{uint32_t i;float f;}v; v.i=u; return v.f; }

// ---------------- merged prep + count_edges, STRIPED (r17 best config) ----------------
// r15: concatenated merge ~= sum (82us). r17: 1/9 stripe hides streaming under the
// atomic storm (70us, best). r19 ERRATum: 1/4 stripe + split counters REGRESSED
// (81us, occupancy 66->33%): storm is bound by raw atomic service throughput; denser
// atomic-block residency only displaces streaming blocks, and splitting the counter
// array doubles its cache-line footprint without raising atomic throughput.
// This is the r17 configuration restored: single counts array, count block every 9th.

__device__ __forceinline__ void swz_one(const float* __restrict__ W, uint16_t* __restrict__ Wf,
                                        int idx, int NCOL, int NTBP){
  int frag = idx >> 9, r = idx & 511, ln = r >> 3, j = r & 7;
  int kb = frag / NTBP, nt = frag - kb*NTBP;
  int k = kb*32 + ((ln >> 4) << 3) + j;
  int n = nt*16 + (ln & 15);
  float w = (n < NCOL) ? W[k*NCOL + n] : 0.f;
  Wf[idx] = f2bf(w);
}

#define PC_COUNT (NE/2)
#define PC_CVT   (PC_COUNT + NN*64)
#define PC_W0    (PC_CVT + 16384)
#define PC_W1    (PC_W0 + 16384)
#define PC_W2    (PC_W1 + 16384)
#define PC_WM1   (PC_W2 + 32768)
#define PC_TOT   (PC_WM1 + 12288)
#define PC_CBLK  (PC_COUNT/256)         // 3125 count blocks
#define PC_NBLK  ((PC_TOT+255)/256)     // 28493 total blocks

__global__ __launch_bounds__(256) void prep_count(const float2* __restrict__ x,
                                                  const int* __restrict__ row,
                                                  int* __restrict__ counts, uint16_t* __restrict__ rank,
                                                  uint32_t* __restrict__ hb,
                                                  const float* __restrict__ W0, uint16_t* __restrict__ W0f,
                                                  const float* __restrict__ W1, uint16_t* __restrict__ W1f,
                                                  const float* __restrict__ W2, uint16_t* __restrict__ W2f,
                                                  const float* __restrict__ Wm1, uint16_t* __restrict__ Wm1f,
                                                  const float* __restrict__ Wm2, uint16_t* __restrict__ Wm2f){
  const int g = blockIdx.x;
  int idx;
  if ((g % 9) == 0 && (g / 9) < PC_CBLK){
    idx = (g/9)*256 + threadIdx.x;                    // count segment [0, PC_COUNT)
  } else {
    int cb = (g + 8) / 9; if (cb > PC_CBLK) cb = PC_CBLK;   // # count blocks before g
    idx = PC_COUNT + (g - cb)*256 + threadIdx.x;      // streaming segments
  }
  if (idx < PC_COUNT){
    int2 r2 = ((const int2*)row)[idx];
    uint16_t a = (uint16_t)atomicAdd(&counts[r2.x], 1);
    uint16_t b = (uint16_t)atomicAdd(&counts[r2.y], 1);
    ((ushort2*)rank)[idx] = make_ushort2(a, b);
  } else if (idx < PC_CVT){
    int i = idx - PC_COUNT;
    float2 v = x[i];
    hb[i] = (uint32_t)f2bf(v.x) | ((uint32_t)f2bf(v.y) << 16);
  } else if (idx < PC_W0){
    swz_one(W0, W0f, idx - PC_CVT, 128, 8);
  } else if (idx < PC_W1){
    swz_one(W1, W1f, idx - PC_W0, 128, 8);
  } else if (idx < PC_W2){
    swz_one(W2, W2f, idx - PC_W1, 128, 8);
  } else if (idx < PC_WM1){
    swz_one(Wm1, Wm1f, idx - PC_W2, 256, 16);
  } else if (idx < PC_TOT){
    swz_one(Wm2, Wm2f, idx - PC_WM1, 40, 3);
  }
}

// ---------------- scan (emits dinv = rsqrt(deg+1)) ----------------

__global__ __launch_bounds__(256) void scan_partial(const int* __restrict__ counts,
                                                    int* __restrict__ offs, int* __restrict__ bsums,
                                                    float* __restrict__ dinv){
  __shared__ int sh[256];
  int t = threadIdx.x, i = blockIdx.x*256 + t;
  int v = (i < NN) ? counts[i] : 0;
  if (i < NN) dinv[i] = rsqrtf((float)(v + 1));
  sh[t] = v; __syncthreads();
  for (int d = 1; d < 256; d <<= 1){
    int x = (t >= d) ? sh[t-d] : 0;
    __syncthreads();
    sh[t] += x;
    __syncthreads();
  }
  if (i < NN) offs[i] = sh[t] - v;
  if (t == 255) bsums[blockIdx.x] = sh[255];
}

__global__ __launch_bounds__(512) void scan_block(int* __restrict__ bsums, int nb){
  __shared__ int sh[512];
  int t = threadIdx.x;
  int v = (t < nb) ? bsums[t] : 0;
  sh[t] = v; __syncthreads();
  for (int d = 1; d < 512; d <<= 1){
    int x = (t >= d) ? sh[t-d] : 0;
    __syncthreads();
    sh[t] += x;
    __syncthreads();
  }
  if (t < nb) bsums[t] = sh[t] - v;
}

__global__ __launch_bounds__(256) void scan_add(int* __restrict__ offs, const int* __restrict__ bsums){
  int i = blockIdx.x*256 + threadIdx.x;
  if (i < NN) offs[i] += bsums[blockIdx.x];
  if (i == 0) offs[NN] = NE;
}

// rank-based fill: atomic-free (round-5 lesson: returning atomics here = 120us)
__global__ __launch_bounds__(256) void fill_csr(const int* __restrict__ row, const int* __restrict__ col,
                                                const uint16_t* __restrict__ rank,
                                                const int* __restrict__ offs,
                                                const float* __restrict__ dinv,
                                                uint2* __restrict__ csr_cw){
  int e2 = blockIdx.x*256 + threadIdx.x;
  if (e2 < NE/2){
    int2 r2 = ((const int2*)row)[e2];
    int2 c2 = ((const int2*)col)[e2];
    ushort2 k2 = ((const ushort2*)rank)[e2];
    int p0 = offs[r2.x] + (int)k2.x;
    int p1 = offs[r2.y] + (int)k2.y;
    uint2 v0, v1;
    v0.x = (uint32_t)c2.x;
    v1.x = (uint32_t)c2.y;
    union{float f;uint32_t i;}w0; w0.f = dinv[c2.x]; v0.y = w0.i;
    union{float f;uint32_t i;}w1; w1.f = dinv[c2.y]; v1.y = w1.i;
    csr_cw[p0] = v0;
    csr_cw[p1] = v1;
  }
}

// ---------------- fused layer: Hout(bf16) = relu( (A_norm @ hb) @ W + b ) ----------------
// Phase 1 scalarized (r6) + 16-deep compiler-scheduled batch (r11: 72.4->70.1us).
// agg is at its multi-resource equilibrium (~70us).

__global__ __launch_bounds__(256) void agg_gemm(const uint32_t* __restrict__ hb,
                                                const int* __restrict__ offs,
                                                const uint2* __restrict__ csr_cw,
                                                const float* __restrict__ dinv,
                                                const uint16_t* __restrict__ Wf,
                                                const float* __restrict__ bias,
                                                uint16_t* __restrict__ Hout){
  __shared__ float lds[16*129];
  __shared__ int ticket;
  const int lane = threadIdx.x & 63;
  const int rbase = blockIdx.x*16;   // NN % 16 == 0, all rows valid
  if (threadIdx.x == 0) ticket = 0;
  __syncthreads();

  // ---- phase 1: dynamic row claim (wave-uniform via readfirstlane) ----
  for (;;){
    int tk = 0;
    if (lane == 0) tk = atomicAdd(&ticket, 1);
    const int rl = __builtin_amdgcn_readfirstlane(tk);
    if (rl >= 16) break;

    const int w = rbase + rl;                  // uniform
    const int s = offs[w], e = offs[w+1];      // uniform -> s_load
    const float dr = dinv[w];                  // uniform -> s_load
    const uint32_t us = hb[((size_t)w << 6) + lane];

    float a0=0.f,a1=0.f,b0=0.f,b1=0.f,c0=0.f,c1=0.f,d0=0.f,d1=0.f;
    float e0=0.f,e1=0.f,f0=0.f,f1=0.f,g0=0.f,g1=0.f,h0=0.f,h1=0.f;
    int i = s;
    // 16-deep: 16 outstanding gathers per wave, compiler-scheduled
    for (; i + 16 <= e; i += 16){
      const uint2 p0=csr_cw[i],   p1=csr_cw[i+1],  p2=csr_cw[i+2],  p3=csr_cw[i+3];
      const uint2 p4=csr_cw[i+4], p5=csr_cw[i+5],  p6=csr_cw[i+6],  p7=csr_cw[i+7];
      const uint2 p8=csr_cw[i+8], p9=csr_cw[i+9],  pa=csr_cw[i+10], pb=csr_cw[i+11];
      const uint2 pc=csr_cw[i+12],pd=csr_cw[i+13], pe=csr_cw[i+14], pf=csr_cw[i+15];
      uint32_t u0=hb[((size_t)p0.x<<6)+lane], u1=hb[((size_t)p1.x<<6)+lane];
      uint32_t u2=hb[((size_t)p2.x<<6)+lane], u3=hb[((size_t)p3.x<<6)+lane];
      uint32_t u4=hb[((size_t)p4.x<<6)+lane], u5=hb[((size_t)p5.x<<6)+lane];
      uint32_t u6=hb[((size_t)p6.x<<6)+lane], u7=hb[((size_t)p7.x<<6)+lane];
      uint32_t u8=hb[((size_t)p8.x<<6)+lane], u9=hb[((size_t)p9.x<<6)+lane];
      uint32_t ua=hb[((size_t)pa.x<<6)+lane], ub=hb[((size_t)pb.x<<6)+lane];
      uint32_t uc=hb[((size_t)pc.x<<6)+lane], ud=hb[((size_t)pd.x<<6)+lane];
      uint32_t ue=hb[((size_t)pe.x<<6)+lane], uf=hb[((size_t)pf.x<<6)+lane];
      a0 += u2f(p0.y)*bfu_lo(u0); a1 += u2f(p0.y)*bfu_hi(u0);
      b0 += u2f(p1.y)*bfu_lo(u1); b1 += u2f(p1.y)*bfu_hi(u1);
      c0 += u2f(p2.y)*bfu_lo(u2); c1 += u2f(p2.y)*bfu_hi(u2);
      d0 += u2f(p3.y)*bfu_lo(u3); d1 += u2f(p3.y)*bfu_hi(u3);
      e0 += u2f(p4.y)*bfu_lo(u4); e1 += u2f(p4.y)*bfu_hi(u4);
      f0 += u2f(p5.y)*bfu_lo(u5); f1 += u2f(p5.y)*bfu_hi(u5);
      g0 += u2f(p6.y)*bfu_lo(u6); g1 += u2f(p6.y)*bfu_hi(u6);
      h0 += u2f(p7.y)*bfu_lo(u7); h1 += u2f(p7.y)*bfu_hi(u7);
      a0 += u2f(p8.y)*bfu_lo(u8); a1 += u2f(p8.y)*bfu_hi(u8);
      b0 += u2f(p9.y)*bfu_lo(u9); b1 += u2f(p9.y)*bfu_hi(u9);
      c0 += u2f(pa.y)*bfu_lo(ua); c1 += u2f(pa.y)*bfu_hi(ua);
      d0 += u2f(pb.y)*bfu_lo(ub); d1 += u2f(pb.y)*bfu_hi(ub);
      e0 += u2f(pc.y)*bfu_lo(uc); e1 += u2f(pc.y)*bfu_hi(uc);
      f0 += u2f(pd.y)*bfu_lo(ud); f1 += u2f(pd.y)*bfu_hi(ud);
      g0 += u2f(pe.y)*bfu_lo(ue); g1 += u2f(pe.y)*bfu_hi(ue);
      h0 += u2f(pf.y)*bfu_lo(uf); h1 += u2f(pf.y)*bfu_hi(uf);
    }
    if (i + 8 <= e){
      const uint2 p0=csr_cw[i],  p1=csr_cw[i+1], p2=csr_cw[i+2], p3=csr_cw[i+3];
      const uint2 p4=csr_cw[i+4],p5=csr_cw[i+5], p6=csr_cw[i+6], p7=csr_cw[i+7];
      uint32_t u0=hb[((size_t)p0.x<<6)+lane], u1=hb[((size_t)p1.x<<6)+lane];
      uint32_t u2=hb[((size_t)p2.x<<6)+lane], u3=hb[((size_t)p3.x<<6)+lane];
      uint32_t u4=hb[((size_t)p4.x<<6)+lane], u5=hb[((size_t)p5.x<<6)+lane];
      uint32_t u6=hb[((size_t)p6.x<<6)+lane], u7=hb[((size_t)p7.x<<6)+lane];
      a0 += u2f(p0.y)*bfu_lo(u0); a1 += u2f(p0.y)*bfu_hi(u0);
      b0 += u2f(p1.y)*bfu_lo(u1); b1 += u2f(p1.y)*bfu_hi(u1);
      c0 += u2f(p2.y)*bfu_lo(u2); c1 += u2f(p2.y)*bfu_hi(u2);
      d0 += u2f(p3.y)*bfu_lo(u3); d1 += u2f(p3.y)*bfu_hi(u3);
      e0 += u2f(p4.y)*bfu_lo(u4); e1 += u2f(p4.y)*bfu_hi(u4);
      f0 += u2f(p5.y)*bfu_lo(u5); f1 += u2f(p5.y)*bfu_hi(u5);
      g0 += u2f(p6.y)*bfu_lo(u6); g1 += u2f(p6.y)*bfu_hi(u6);
      h0 += u2f(p7.y)*bfu_lo(u7); h1 += u2f(p7.y)*bfu_hi(u7);
      i += 8;
    }
    if (i + 4 <= e){
      const uint2 p0=csr_cw[i], p1=csr_cw[i+1], p2=csr_cw[i+2], p3=csr_cw[i+3];
      uint32_t u0=hb[((size_t)p0.x<<6)+lane], u1=hb[((size_t)p1.x<<6)+lane];
      uint32_t u2=hb[((size_t)p2.x<<6)+lane], u3=hb[((size_t)p3.x<<6)+lane];
      a0 += u2f(p0.y)*bfu_lo(u0); a1 += u2f(p0.y)*bfu_hi(u0);
      b0 += u2f(p1.y)*bfu_lo(u1); b1 += u2f(p1.y)*bfu_hi(u1);
      c0 += u2f(p2.y)*bfu_lo(u2); c1 += u2f(p2.y)*bfu_hi(u2);
      d0 += u2f(p3.y)*bfu_lo(u3); d1 += u2f(p3.y)*bfu_hi(u3);
      i += 4;
    }
    for (; i < e; ++i){
      const uint2 p = csr_cw[i];
      uint32_t u = hb[((size_t)p.x<<6) + lane];
      a0 += u2f(p.y)*bfu_lo(u); a1 += u2f(p.y)*bfu_hi(u);
    }
    float r0 = (((a0+b0)+(c0+d0)) + ((e0+f0)+(g0+h0))) + dr*bfu_lo(us);
    float r1 = (((a1+b1)+(c1+d1)) + ((e1+f1)+(g1+h1))) + dr*bfu_hi(us);
    lds[rl*129 + 2*lane]     = r0*dr;
    lds[rl*129 + 2*lane + 1] = r1*dr;
  }
  __syncthreads();

  // ---- phase 2: 16x128 GEMM tile; this wave covers n-tiles 2*wid, 2*wid+1 ----
  const int wid = threadIdx.x >> 6;
  const int mr = lane & 15;
  const int ko = (lane >> 4) << 3;
  float4v acc[2];
  { float4v z = {0.f,0.f,0.f,0.f}; acc[0] = z; acc[1] = z; }
#pragma unroll
  for (int kb = 0; kb < 4; ++kb){
    short8 ah, al;
#pragma unroll
    for (int j = 0; j < 8; ++j){
      float f = lds[mr*129 + kb*32 + ko + j];
      short h, l; split2(f, h, l); ah[j] = h; al[j] = l;
    }
#pragma unroll
    for (int t = 0; t < 2; ++t){
      int nt = wid*2 + t;
      short8 bf = *(const short8*)&Wf[(kb*8 + nt)*512 + lane*8];
      acc[t] = __builtin_amdgcn_mfma_f32_16x16x32_bf16(ah, bf, acc[t], 0, 0, 0);
      acc[t] = __builtin_amdgcn_mfma_f32_16x16x32_bf16(al, bf, acc[t], 0, 0, 0);
    }
  }
  const int col = lane & 15;
  const int rb  = (lane >> 4) * 4;
#pragma unroll
  for (int t = 0; t < 2; ++t){
    int n = (wid*2 + t)*16 + col;
    float bv = bias[n];
#pragma unroll
    for (int r = 0; r < 4; ++r){
      int m = rbase + rb + r;
      float v = acc[t][r] + bv;
      Hout[(size_t)m*128 + n] = f2bf(v > 0.f ? v : 0.f);
    }
  }
}

// ---------------- fused MLP: 2 m-tiles/wave, bf16 weights (1-term), stride-260 LDS ----------------

#define HS 260

__global__ __launch_bounds__(256) void mlp_fused(const uint16_t* __restrict__ Hb,
                                                 const uint16_t* __restrict__ W1f,
                                                 const float* __restrict__ b1,
                                                 const uint16_t* __restrict__ W2f,
                                                 const float* __restrict__ b2,
                                                 float* __restrict__ out, int M){
  __shared__ uint16_t hid[128*HS];
  const int lane = threadIdx.x & 63;
  const int wid = threadIdx.x >> 6;
  const int mbase = blockIdx.x*128 + wid*32;
  const int mr = lane & 15;
  const int a0r = (mbase + mr < M) ? (mbase + mr) : (M-1);
  const int a1r = (mbase + 16 + mr < M) ? (mbase + 16 + mr) : (M-1);
  const int ko = (lane >> 4) << 3;
  const int col = lane & 15;
  const int rb  = (lane >> 4) * 4;

  float4v acc1[16][2];
#pragma unroll
  for (int nt = 0; nt < 16; ++nt){ float4v z = {0.f,0.f,0.f,0.f}; acc1[nt][0] = z; acc1[nt][1] = z; }
#pragma unroll
  for (int kb = 0; kb < 4; ++kb){
    short8 af0 = *(const short8*)&Hb[(size_t)a0r*128 + kb*32 + ko];
    short8 af1 = *(const short8*)&Hb[(size_t)a1r*128 + kb*32 + ko];
#pragma unroll
    for (int nt = 0; nt < 16; ++nt){
      short8 bf = *(const short8*)&W1f[(kb*16 + nt)*512 + lane*8];
      acc1[nt][0] = __builtin_amdgcn_mfma_f32_16x16x32_bf16(af0, bf, acc1[nt][0], 0, 0, 0);
      acc1[nt][1] = __builtin_amdgcn_mfma_f32_16x16x32_bf16(af1, bf, acc1[nt][1], 0, 0, 0);
    }
  }
#pragma unroll
  for (int nt = 0; nt < 16; ++nt){
    float bv = b1[nt*16 + col];
#pragma unroll
    for (int mt = 0; mt < 2; ++mt){
#pragma unroll
      for (int r = 0; r < 4; ++r){
        float v = acc1[nt][mt][r] + bv;
        v = v > 0.f ? v : 0.f;
        hid[(wid*32 + mt*16 + rb + r)*HS + nt*16 + col] = f2bf(v);
      }
    }
  }
  __syncthreads();

  float4v acc2[3][2];
#pragma unroll
  for (int nt = 0; nt < 3; ++nt){ float4v z = {0.f,0.f,0.f,0.f}; acc2[nt][0] = z; acc2[nt][1] = z; }
#pragma unroll
  for (int kb = 0; kb < 8; ++kb){
    short8 a0 = *(const short8*)&hid[(wid*32 + mr)*HS + kb*32 + ko];
    short8 a1 = *(const short8*)&hid[(wid*32 + 16 + mr)*HS + kb*32 + ko];
#pragma unroll
    for (int nt = 0; nt < 3; ++nt){
      short8 bf = *(const short8*)&W2f[(kb*3 + nt)*512 + lane*8];
      acc2[nt][0] = __builtin_amdgcn_mfma_f32_16x16x32_bf16(a0, bf, acc2[nt][0], 0, 0, 0);
      acc2[nt][1] = __builtin_amdgcn_mfma_f32_16x16x32_bf16(a1, bf, acc2[nt][1], 0, 0, 0);
    }
  }
#pragma unroll
  for (int nt = 0; nt < 3; ++nt){
    int n = nt*16 + col;
    if (n < LL){
      float bv = b2[n];
#pragma unroll
      for (int mt = 0; mt < 2; ++mt){
#pragma unroll
        for (int r = 0; r < 4; ++r){
          int m = mbase + mt*16 + rb + r;
          if (m < M) out[(size_t)m*LL + n] = acc2[nt][mt][r] + bv;
        }
      }
    }
  }
}

// ---------------- launch ----------------

extern "C" void kernel_launch(void* const* d_in, const int* in_sizes, int n_in,
                              void* d_out, int out_size, void* d_ws, size_t ws_size,
                              hipStream_t stream){
  const float* x   = (const float*)d_in[0];
  const int*   ei  = (const int*)d_in[1];
  const float* W0  = (const float*)d_in[2];
  const float* b0  = (const float*)d_in[3];
  const float* W1  = (const float*)d_in[4];
  const float* b1  = (const float*)d_in[5];
  const float* W2  = (const float*)d_in[6];
  const float* b2  = (const float*)d_in[7];
  const float* Wm1 = (const float*)d_in[8];
  const float* bm1 = (const float*)d_in[9];
  const float* Wm2 = (const float*)d_in[10];
  const float* bm2 = (const float*)d_in[11];
  const int* row = ei;
  const int* col = ei + NE;

  char* ws = (char*)d_ws;
  size_t off = 0;
  auto alloc = [&](size_t bytes)->void*{
    void* p = ws + off;
    off += (bytes + 255) & ~(size_t)255;
    return p;
  };
  int*      counts  = (int*)alloc((size_t)NN*4);
  int*      offs    = (int*)alloc(((size_t)NN+1)*4);
  int*      bsums   = (int*)alloc(1024*4);
  float*    dinv    = (float*)alloc((size_t)NN*4);
  uint16_t* rank    = (uint16_t*)alloc((size_t)NE*2);
  uint2*    csr_cw  = (uint2*)alloc((size_t)NE*8);
  uint16_t* W0f     = (uint16_t*)alloc(4*8*512*2);
  uint16_t* W1f     = (uint16_t*)alloc(4*8*512*2);
  uint16_t* W2f     = (uint16_t*)alloc(4*8*512*2);
  uint16_t* Wm1f    = (uint16_t*)alloc(4*16*512*2);
  uint16_t* Wm2f    = (uint16_t*)alloc(8*3*512*2);
  uint16_t* hb      = (uint16_t*)alloc((size_t)NN*DD*2);
  uint16_t* hb2     = (uint16_t*)alloc((size_t)NN*DD*2);

  hipMemsetAsync(counts, 0, (size_t)NN*4, stream);
  prep_count<<<PC_NBLK, 256, 0, stream>>>((const float2*)x, row, counts, rank, (uint32_t*)hb,
                                          W0, W0f, W1, W1f, W2, W2f, Wm1, Wm1f, Wm2, Wm2f);
  const int NB = (NN+255)/256;
  scan_partial<<<NB, 256, 0, stream>>>(counts, offs, bsums, dinv);
  scan_block<<<1, 512, 0, stream>>>(bsums, NB);
  scan_add<<<NB, 256, 0, stream>>>(offs, bsums);
  fill_csr<<<(NE/2+255)/256, 256, 0, stream>>>(row, col, rank, offs, dinv, csr_cw);

  const int LB = NN/16;   // 6250 blocks, 16 rows each

  agg_gemm<<<LB, 256, 0, stream>>>((const uint32_t*)hb,  offs, csr_cw, dinv, W0f, b0, hb2);
  agg_gemm<<<LB, 256, 0, stream>>>((const uint32_t*)hb2, offs, csr_cw, dinv, W1f, b1, hb);
  agg_gemm<<<LB, 256, 0, stream>>>((const uint32_t*)hb,  offs, csr_cw, dinv, W2f, b2, hb2);

  const int GB128 = (NN + 127)/128;
  mlp_fused<<<GB128, 256, 0, stream>>>(hb2, Wm1f, bm1, Wm2f, bm2, (float*)d_out, NN);
}